// Round 3
// baseline (180.452 us; speedup 1.0000x reference)
//
#include <hip/hip_runtime.h>
#include <math.h>

#define N_NODES 50000
#define N_EDGES 600000
#define DIM 128
#define BCAP 64     // bucket capacity; P(Poisson(12) > 64) ~ 1e-28
#define CPAD 16     // cursor padding: one counter per 64B line (atomic RMWs
                    // serialize per LINE at the coherence point; unpadded =
                    // 192 RMWs/line chain, padded = 12)

typedef __attribute__((ext_vector_type(8))) short bf16x8;
typedef __attribute__((ext_vector_type(4))) float f32x4;

// HW packed f32->bf16 RNE: dst[15:0]=bf16(a), dst[31:16]=bf16(b).
static __device__ __forceinline__ unsigned cvt_pk_bf16(float a, float b) {
    unsigned r;
    asm("v_cvt_pk_bf16_f32 %0, %1, %2" : "=v"(r) : "v"(a), "v"(b));
    return r;
}
static __device__ __forceinline__ unsigned short f2bf(float f) {
    return (unsigned short)cvt_pk_bf16(f, f);
}

// unpack one u32 (two bf16) -> two floats
#define UNPK(w, d0, d1)                         \
    d0 = __uint_as_float((w) << 16);            \
    d1 = __uint_as_float((w) & 0xFFFF0000u);

// sum across each 16-lane row via DPP (VALU pipe; no LDS latency).
#define DPPADD(x, ctrl)                                                          \
    x += __int_as_float(__builtin_amdgcn_mov_dpp(__float_as_int(x), ctrl,        \
                                                 0xF, 0xF, true));
static __device__ __forceinline__ float row_sum16(float x) {
    DPPADD(x, 0xB1)    // quad_perm [1,0,3,2]  (xor 1)
    DPPADD(x, 0x4E)    // quad_perm [2,3,0,1]  (xor 2)
    DPPADD(x, 0x141)   // row_half_mirror
    DPPADD(x, 0x140)   // row_mirror
    return x;
}

// ---------------- prep: zero counters/cursors + convert W to bf16
__global__ __launch_bounds__(256) void prep_kernel(const float* __restrict__ W,
                                                   unsigned short* __restrict__ Wb,
                                                   int* __restrict__ curp,
                                                   int* __restrict__ cnt) {
    int gid = blockIdx.x * 256 + threadIdx.x;
    if (gid < N_NODES) {
        curp[gid * CPAD] = 0;
        cnt[gid] = 0;
    }
    if (gid < DIM * DIM) Wb[gid] = f2bf(W[gid]);
}

// ---------------- gemm body: z = h @ W^T via bf16 MFMA, fp32 acc, bf16 out
static __device__ __forceinline__ void gemm_body(const float* __restrict__ h,
                                                 const unsigned short* __restrict__ Wb,
                                                 unsigned short* __restrict__ zb,
                                                 int wave, int lane) {
    int lo = lane & 15;
    int hi = lane >> 4;
    long row0 = (long)wave * 16;

    bf16x8 afrag[4];
    const float* arow = h + (row0 + lo) * DIM;
    #pragma unroll
    for (int kt = 0; kt < 4; ++kt) {
        const float* ap = arow + kt * 32 + hi * 8;
        float4 f0 = *(const float4*)ap;
        float4 f1 = *(const float4*)(ap + 4);
        union { unsigned u[4]; bf16x8 v; } c;
        c.u[0] = cvt_pk_bf16(f0.x, f0.y);
        c.u[1] = cvt_pk_bf16(f0.z, f0.w);
        c.u[2] = cvt_pk_bf16(f1.x, f1.y);
        c.u[3] = cvt_pk_bf16(f1.z, f1.w);
        afrag[kt] = c.v;
    }

    #pragma unroll
    for (int ct = 0; ct < 8; ++ct) {
        f32x4 acc = {0.f, 0.f, 0.f, 0.f};
        const unsigned short* brow = Wb + (ct * 16 + lo) * DIM + hi * 8;
        #pragma unroll
        for (int kt = 0; kt < 4; ++kt) {
            bf16x8 b = *(const bf16x8*)(brow + kt * 32);
            acc = __builtin_amdgcn_mfma_f32_16x16x32_bf16(afrag[kt], b, acc, 0, 0, 0);
        }
        // D: row = hi*4 + r, col = lo  (m89-verified C/D layout)
        unsigned short* zp = zb + (row0 + hi * 4) * DIM + ct * 16 + lo;
        zp[0 * DIM] = f2bf(acc[0]);
        zp[1 * DIM] = f2bf(acc[1]);
        zp[2 * DIM] = f2bf(acc[2]);
        zp[3 * DIM] = f2bf(acc[3]);
    }
}

// Concurrent fill || gemm via block-role partition (bid%4==0 -> gemm).
__global__ __launch_bounds__(256) void fg_kernel(const float* __restrict__ h,
                                                 const unsigned short* __restrict__ Wb,
                                                 unsigned short* __restrict__ zb,
                                                 const int* __restrict__ src,
                                                 const int* __restrict__ dst,
                                                 int* __restrict__ curp,
                                                 int* __restrict__ lst) {
    int bid = blockIdx.x;
    if (bid & 3) {
        int f = (bid >> 2) * 3 + (bid & 3) - 1;   // fill-block index 0..2343
        int i = f * 256 + threadIdx.x;
        if (i < N_EDGES) {
            int d = dst[i];
            int pos = atomicAdd(curp + d * CPAD, 1);
            if (pos < BCAP) lst[d * BCAP + pos] = src[i];
        }
        return;
    }
    int wave = (bid >> 2) * 4 + (threadIdx.x >> 6);
    if (wave >= N_NODES / 16) return;
    gemm_body(h, Wb, zb, wave, threadIdx.x & 63);
}

// standalone gemm for the CSR fallback path
__global__ __launch_bounds__(256) void gemm_kernel(const float* __restrict__ h,
                                                   const unsigned short* __restrict__ Wb,
                                                   unsigned short* __restrict__ zb) {
    int wave = blockIdx.x * 4 + (threadIdx.x >> 6);
    if (wave >= N_NODES / 16) return;
    gemm_body(h, Wb, zb, wave, threadIdx.x & 63);
}

// ---------------- CSR fallback path: count / scan / fill
__global__ __launch_bounds__(256) void count_kernel(const int* __restrict__ dst,
                                                    int* __restrict__ cnt) {
    int i = blockIdx.x * 256 + threadIdx.x;
    if (i < N_EDGES) atomicAdd(cnt + dst[i], 1);
}

__global__ __launch_bounds__(256) void scan_a(const int* __restrict__ cnt,
                                              int* __restrict__ incl,
                                              int* __restrict__ bsum) {
    __shared__ int s[256];
    int i = blockIdx.x * 256 + threadIdx.x;
    s[threadIdx.x] = (i < N_NODES) ? cnt[i] : 0;
    __syncthreads();
    #pragma unroll
    for (int off = 1; off < 256; off <<= 1) {
        int t = (threadIdx.x >= off) ? s[threadIdx.x - off] : 0;
        __syncthreads();
        s[threadIdx.x] += t;
        __syncthreads();
    }
    if (i < N_NODES) incl[i] = s[threadIdx.x];
    if (threadIdx.x == 255) bsum[blockIdx.x] = s[255];
}

__global__ __launch_bounds__(256) void scan_b(int* __restrict__ bsum, int nb) {
    __shared__ int s[256];
    s[threadIdx.x] = (threadIdx.x < nb) ? bsum[threadIdx.x] : 0;
    __syncthreads();
    #pragma unroll
    for (int off = 1; off < 256; off <<= 1) {
        int t = (threadIdx.x >= off) ? s[threadIdx.x - off] : 0;
        __syncthreads();
        s[threadIdx.x] += t;
        __syncthreads();
    }
    if (threadIdx.x < nb) bsum[threadIdx.x] = s[threadIdx.x];
}

__global__ __launch_bounds__(256) void scan_c(int* __restrict__ incl_off,
                                              const int* __restrict__ cnt,
                                              const int* __restrict__ bsum) {
    int i = blockIdx.x * 256 + threadIdx.x;
    if (i >= N_NODES) return;
    int base = (blockIdx.x > 0) ? bsum[blockIdx.x - 1] : 0;
    incl_off[i] = incl_off[i] - cnt[i] + base;
}

__global__ __launch_bounds__(256) void cfill_kernel(const int* __restrict__ src,
                                                    const int* __restrict__ dst,
                                                    const int* __restrict__ off,
                                                    int* __restrict__ curp,
                                                    int* __restrict__ lst) {
    int i = blockIdx.x * 256 + threadIdx.x;
    if (i >= N_EDGES) return;
    int d = dst[i];
    int pos = atomicAdd(curp + d * CPAD, 1);
    lst[off[d] + pos] = src[i];
}

// ---------------- fused per-node: scores + softmax (no-max) + gather, bf16 z.
// One node per 16-lane quarter; 16 gather slots issued UP-FRONT per chunk so
// a deg<=16 node (89% of Poisson(12) mass) is ONE memory round-trip.
__global__ __launch_bounds__(256) void node_kernel(const unsigned short* __restrict__ zb,
                                                   const int* __restrict__ lst,
                                                   const int* __restrict__ off,
                                                   const int* __restrict__ degp,
                                                   int dstride,   // CPAD bucket / 1 csr
                                                   int stride,    // BCAP bucket / 0 csr
                                                   const float* __restrict__ beta,
                                                   float* __restrict__ out) {
    int wid  = blockIdx.x * 4 + (threadIdx.x >> 6);
    int lane = threadIdx.x & 63;
    int q    = lane >> 4;
    int ql   = lane & 15;
    int node = wid * 4 + q;
    if (node >= N_NODES) return;
    int deg = degp[node * dstride];
    int start;
    if (stride > 0) {
        if (deg > BCAP) deg = BCAP;   // impossible for Poisson(12); OOB guard
        start = node * stride;
    } else {
        start = off[node];
    }
    float nbet = -beta[0];

    // zd dims ql*8..+7 : 16 lanes cover the 128-dim row of this quarter's node
    uint4 zdw = *(const uint4*)(zb + (long)node * DIM + ql * 8);
    float zd[8];
    UNPK(zdw.x, zd[0], zd[1]) UNPK(zdw.y, zd[2], zd[3])
    UNPK(zdw.z, zd[4], zd[5]) UNPK(zdw.w, zd[6], zd[7])

    float sden = 0.0f;
    float acc[8];
    #pragma unroll
    for (int i = 0; i < 8; ++i) acc[i] = 0.0f;

    for (int cb = 0; cb < deg; cb += 16) {
        int nch = deg - cb;
        if (nch > 16) nch = 16;
        // lane ql of this quarter holds src id of edge cb+ql
        int sj = (ql < nch) ? lst[start + cb + ql] : 0;

        // broadcast all 16 slots, then issue ALL 16 gathers back-to-back:
        // 16 outstanding vmem ops per lane -> single latency chain per chunk
        int sv[16];
        #pragma unroll
        for (int k = 0; k < 16; ++k)
            sv[k] = __shfl(sj, q * 16 + k, 64);
        uint4 aw[16];
        #pragma unroll
        for (int k = 0; k < 16; ++k)
            aw[k] = *(const uint4*)(zb + (long)sv[k] * DIM + ql * 8);

        #pragma unroll
        for (int k = 0; k < 16; ++k) {
            float a[8];
            UNPK(aw[k].x, a[0], a[1]) UNPK(aw[k].y, a[2], a[3])
            UNPK(aw[k].z, a[4], a[5]) UNPK(aw[k].w, a[6], a[7])
            float p = 0.0f;
            #pragma unroll
            for (int i = 0; i < 8; ++i) {
                float d = a[i] - zd[i];
                p += d * d;
            }
            p = row_sum16(p);                 // full ||z_s - z_d||^2
            float w = (k < nch)
                    ? __expf(nbet * __builtin_amdgcn_sqrtf(p + 1e-12f))
                    : 0.0f;
            sden += w;
            #pragma unroll
            for (int i = 0; i < 8; ++i) acc[i] += w * a[i];
        }
    }

    float inv = (deg > 0) ? 1.0f / sden : 0.0f;
    float* orow = out + (long)node * DIM + ql * 8;
    *(float4*)orow =
        make_float4(acc[0] * inv, acc[1] * inv, acc[2] * inv, acc[3] * inv);
    *(float4*)(orow + 4) =
        make_float4(acc[4] * inv, acc[5] * inv, acc[6] * inv, acc[7] * inv);
}

extern "C" void kernel_launch(void* const* d_in, const int* in_sizes, int n_in,
                              void* d_out, int out_size, void* d_ws, size_t ws_size,
                              hipStream_t stream) {
    const float* h    = (const float*)d_in[0];
    const float* W    = (const float*)d_in[1];
    const float* beta = (const float*)d_in[2];
    const int* src    = (const int*)d_in[3];
    const int* dst    = (const int*)d_in[4];
    float* out = (float*)d_out;

    // workspace (4B word units).  zb = 50000*128 bf16 = 6.4M shorts = 3.2M WORDS
    //   zb    [0, 3.2M)
    //   lst   [3.2M, 3.2M+L)            bucket 3.2M or csr 600k
    //   curp  50000*CPAD = 800k words   (64B-padded atomic cursors)
    //   cnt / off / bsum / Wb after
    const size_t bucket_total =
        (3200000ull + 3200000 + 50000ull * CPAD + 100000 + 256 + 8192) * 4;
    const bool use_bucket = ws_size >= bucket_total;
    const size_t lst_len = use_bucket ? 3200000 : 600000;

    float* ws  = (float*)d_ws;
    unsigned short* zb = (unsigned short*)ws;            // 3,200,000 words
    int* lst   = (int*)(ws + 3200000);                   // bucket 3.2M or csr 600k
    int* curp  = (int*)(ws + 3200000 + lst_len);         // 50,000 * CPAD
    int* cnt   = curp + 50000 * CPAD;                    // 50,000
    int* off   = cnt + 50000;                            // 50,000
    int* bsum  = off + 50000;                            //    256
    unsigned short* Wb = (unsigned short*)(bsum + 256);  // 16,384 bf16

    const int node_blocks = N_NODES / 16;                // 3125 (16 nodes/block)

    prep_kernel<<<196, 256, 0, stream>>>(W, Wb, curp, cnt);
    if (use_bucket) {
        // 3126 blocks: bid%4==0 -> gemm (782), else -> fill (2344)
        fg_kernel<<<3126, 256, 0, stream>>>(h, Wb, zb, src, dst, curp, lst);
        node_kernel<<<node_blocks, 256, 0, stream>>>(zb, lst, off /*unused*/, curp,
                                                     CPAD, BCAP, beta, out);
    } else {
        count_kernel<<<(N_EDGES + 255) / 256, 256, 0, stream>>>(dst, cnt);
        scan_a<<<196, 256, 0, stream>>>(cnt, off, bsum);
        scan_b<<<1, 256, 0, stream>>>(bsum, 196);
        scan_c<<<196, 256, 0, stream>>>(off, cnt, bsum);
        cfill_kernel<<<(N_EDGES + 255) / 256, 256, 0, stream>>>(src, dst, off, curp, lst);
        gemm_kernel<<<(N_NODES / 16 + 3) / 4, 256, 0, stream>>>(h, Wb, zb);
        node_kernel<<<node_blocks, 256, 0, stream>>>(zb, lst, off, cnt,
                                                     1, 0, beta, out);
    }
}

// Round 4
// 170.818 us; speedup vs baseline: 1.0564x; 1.0564x over previous
//
#include <hip/hip_runtime.h>
#include <math.h>

#define N_NODES 50000
#define N_EDGES 600000
#define DIM 128
#define BCAP 64   // bucket capacity; P(Poisson(12) > 64) ~ 1e-28

typedef __attribute__((ext_vector_type(8))) short bf16x8;
typedef __attribute__((ext_vector_type(4))) float f32x4;

// HW packed f32->bf16 RNE (identical bits to the bit-twiddle path; absmax
// constant across rounds confirms). 1 VALU op per 2 elements.
static __device__ __forceinline__ unsigned cvt_pk_bf16(float a, float b) {
    unsigned r;
    asm("v_cvt_pk_bf16_f32 %0, %1, %2" : "=v"(r) : "v"(a), "v"(b));
    return r;
}
static __device__ __forceinline__ unsigned short f2bf(float f) {
    return (unsigned short)cvt_pk_bf16(f, f);
}

// unpack one u32 (two bf16) -> two floats
#define UNPK(w, d0, d1)                         \
    d0 = __uint_as_float((w) << 16);            \
    d1 = __uint_as_float((w) & 0xFFFF0000u);

// sum across each 16-lane row via DPP (VALU pipe; no LDS latency).
#define DPPADD(x, ctrl)                                                          \
    x += __int_as_float(__builtin_amdgcn_mov_dpp(__float_as_int(x), ctrl,        \
                                                 0xF, 0xF, true));
static __device__ __forceinline__ float row_sum16(float x) {
    DPPADD(x, 0xB1)    // quad_perm [1,0,3,2]  (xor 1)
    DPPADD(x, 0x4E)    // quad_perm [2,3,0,1]  (xor 2)
    DPPADD(x, 0x141)   // row_half_mirror
    DPPADD(x, 0x140)   // row_mirror
    return x;
}

// ---------------- prep: zero counters/cursors + convert W to bf16
__global__ __launch_bounds__(256) void prep_kernel(const float* __restrict__ W,
                                                   unsigned short* __restrict__ Wb,
                                                   int* __restrict__ cur,
                                                   int* __restrict__ cnt) {
    int gid = blockIdx.x * 256 + threadIdx.x;
    if (gid < N_NODES) {
        cur[gid] = 0;
        cnt[gid] = 0;
    }
    if (gid < DIM * DIM) Wb[gid] = f2bf(W[gid]);
}

// ---------------- gemm body: z = h @ W^T via bf16 MFMA, fp32 acc, bf16 out
static __device__ __forceinline__ void gemm_body(const float* __restrict__ h,
                                                 const unsigned short* __restrict__ Wb,
                                                 unsigned short* __restrict__ zb,
                                                 int wave, int lane) {
    int lo = lane & 15;
    int hi = lane >> 4;
    long row0 = (long)wave * 16;

    bf16x8 afrag[4];
    const float* arow = h + (row0 + lo) * DIM;
    #pragma unroll
    for (int kt = 0; kt < 4; ++kt) {
        const float* ap = arow + kt * 32 + hi * 8;
        float4 f0 = *(const float4*)ap;
        float4 f1 = *(const float4*)(ap + 4);
        union { unsigned u[4]; bf16x8 v; } c;
        c.u[0] = cvt_pk_bf16(f0.x, f0.y);
        c.u[1] = cvt_pk_bf16(f0.z, f0.w);
        c.u[2] = cvt_pk_bf16(f1.x, f1.y);
        c.u[3] = cvt_pk_bf16(f1.z, f1.w);
        afrag[kt] = c.v;
    }

    #pragma unroll
    for (int ct = 0; ct < 8; ++ct) {
        f32x4 acc = {0.f, 0.f, 0.f, 0.f};
        const unsigned short* brow = Wb + (ct * 16 + lo) * DIM + hi * 8;
        #pragma unroll
        for (int kt = 0; kt < 4; ++kt) {
            bf16x8 b = *(const bf16x8*)(brow + kt * 32);
            acc = __builtin_amdgcn_mfma_f32_16x16x32_bf16(afrag[kt], b, acc, 0, 0, 0);
        }
        // D: row = hi*4 + r, col = lo  (m89-verified C/D layout)
        unsigned short* zp = zb + (row0 + hi * 4) * DIM + ct * 16 + lo;
        zp[0 * DIM] = f2bf(acc[0]);
        zp[1 * DIM] = f2bf(acc[1]);
        zp[2 * DIM] = f2bf(acc[2]);
        zp[3 * DIM] = f2bf(acc[3]);
    }
}

// Concurrent fill || gemm via block-role partition (bid%4==0 -> gemm).
// Measured: 74 us vs 79 us in-wave-serial; keep.
__global__ __launch_bounds__(256) void fg_kernel(const float* __restrict__ h,
                                                 const unsigned short* __restrict__ Wb,
                                                 unsigned short* __restrict__ zb,
                                                 const int* __restrict__ src,
                                                 const int* __restrict__ dst,
                                                 int* __restrict__ cur,
                                                 int* __restrict__ lst) {
    int bid = blockIdx.x;
    if (bid & 3) {
        int f = (bid >> 2) * 3 + (bid & 3) - 1;   // fill-block index 0..2343
        int i = f * 256 + threadIdx.x;
        if (i < N_EDGES) {
            int d = dst[i];
            int pos = atomicAdd(cur + d, 1);
            if (pos < BCAP) lst[d * BCAP + pos] = src[i];
        }
        return;
    }
    int wave = (bid >> 2) * 4 + (threadIdx.x >> 6);
    if (wave >= N_NODES / 16) return;
    gemm_body(h, Wb, zb, wave, threadIdx.x & 63);
}

// standalone gemm for the CSR fallback path
__global__ __launch_bounds__(256) void gemm_kernel(const float* __restrict__ h,
                                                   const unsigned short* __restrict__ Wb,
                                                   unsigned short* __restrict__ zb) {
    int wave = blockIdx.x * 4 + (threadIdx.x >> 6);
    if (wave >= N_NODES / 16) return;
    gemm_body(h, Wb, zb, wave, threadIdx.x & 63);
}

// ---------------- CSR fallback path: count / scan / fill
__global__ __launch_bounds__(256) void count_kernel(const int* __restrict__ dst,
                                                    int* __restrict__ cnt) {
    int i = blockIdx.x * 256 + threadIdx.x;
    if (i < N_EDGES) atomicAdd(cnt + dst[i], 1);
}

__global__ __launch_bounds__(256) void scan_a(const int* __restrict__ cnt,
                                              int* __restrict__ incl,
                                              int* __restrict__ bsum) {
    __shared__ int s[256];
    int i = blockIdx.x * 256 + threadIdx.x;
    s[threadIdx.x] = (i < N_NODES) ? cnt[i] : 0;
    __syncthreads();
    #pragma unroll
    for (int off = 1; off < 256; off <<= 1) {
        int t = (threadIdx.x >= off) ? s[threadIdx.x - off] : 0;
        __syncthreads();
        s[threadIdx.x] += t;
        __syncthreads();
    }
    if (i < N_NODES) incl[i] = s[threadIdx.x];
    if (threadIdx.x == 255) bsum[blockIdx.x] = s[255];
}

__global__ __launch_bounds__(256) void scan_b(int* __restrict__ bsum, int nb) {
    __shared__ int s[256];
    s[threadIdx.x] = (threadIdx.x < nb) ? bsum[threadIdx.x] : 0;
    __syncthreads();
    #pragma unroll
    for (int off = 1; off < 256; off <<= 1) {
        int t = (threadIdx.x >= off) ? s[threadIdx.x - off] : 0;
        __syncthreads();
        s[threadIdx.x] += t;
        __syncthreads();
    }
    if (threadIdx.x < nb) bsum[threadIdx.x] = s[threadIdx.x];
}

__global__ __launch_bounds__(256) void scan_c(int* __restrict__ incl_off,
                                              const int* __restrict__ cnt,
                                              const int* __restrict__ bsum) {
    int i = blockIdx.x * 256 + threadIdx.x;
    if (i >= N_NODES) return;
    int base = (blockIdx.x > 0) ? bsum[blockIdx.x - 1] : 0;
    incl_off[i] = incl_off[i] - cnt[i] + base;
}

__global__ __launch_bounds__(256) void cfill_kernel(const int* __restrict__ src,
                                                    const int* __restrict__ dst,
                                                    const int* __restrict__ off,
                                                    int* __restrict__ cur,
                                                    int* __restrict__ lst) {
    int i = blockIdx.x * 256 + threadIdx.x;
    if (i >= N_EDGES) return;
    int d = dst[i];
    int pos = atomicAdd(cur + d, 1);
    lst[off[d] + pos] = src[i];
}

// ---------------- fused per-node: scores + softmax (no-max) + gather, bf16 z.
// ROUND-0 STRUCTURE (best measured): one node per WAVE, 16 lanes per edge,
// 2x unrolled => 8 edges per iteration, all 4 quarters share the same rows'
// cache lines. Quarter-per-node and deeper unrolls both measured WORSE
// (rounds 2-3): the limiter is memory-side random-gather service rate, which
// favors more waves + shared lines over per-wave ILP.
__global__ __launch_bounds__(256) void node_kernel(const unsigned short* __restrict__ zb,
                                                   const int* __restrict__ lst,
                                                   const int* __restrict__ off,
                                                   const int* __restrict__ degp,
                                                   int stride,
                                                   const float* __restrict__ beta,
                                                   float* __restrict__ out) {
    int node = blockIdx.x * 4 + (threadIdx.x >> 6);
    if (node >= N_NODES) return;
    int lane = threadIdx.x & 63;
    int q = lane >> 4;
    int ql = lane & 15;
    int deg = degp[node];
    int start;
    if (stride > 0) {
        if (deg > BCAP) deg = BCAP;   // impossible for Poisson(12); OOB guard
        start = node * stride;
    } else {
        start = off[node];
    }
    float nbet = -beta[0];

    // zd dims ql*8..+7 (all 4 quarters read the same 256B row -> broadcast)
    uint4 zdw = *(const uint4*)(zb + (long)node * DIM + ql * 8);
    float zd[8];
    UNPK(zdw.x, zd[0], zd[1]) UNPK(zdw.y, zd[2], zd[3])
    UNPK(zdw.z, zd[4], zd[5]) UNPK(zdw.w, zd[6], zd[7])

    float sden = 0.0f;     // per-quarter partial denom
    float acc[8];
    #pragma unroll
    for (int i = 0; i < 8; ++i) acc[i] = 0.0f;

    for (int cb = 0; cb < deg; cb += 64) {
        int nch = deg - cb;
        if (nch > 64) nch = 64;
        int sj = (lane < nch) ? lst[start + cb + lane] : 0;   // lane j: src of edge j

        for (int jb = 0; jb < nch; jb += 8) {
            int jo0 = jb + q;                   // this quarter's two edge slots
            int jo1 = jb + 4 + q;
            bool v0 = jo0 < nch;
            bool v1 = jo1 < nch;
            int s0 = __shfl(sj, v0 ? jo0 : 0, 64);
            int s1 = __shfl(sj, v1 ? jo1 : 0, 64);
            uint4 aw0 = *(const uint4*)(zb + (long)s0 * DIM + ql * 8);
            uint4 aw1 = *(const uint4*)(zb + (long)s1 * DIM + ql * 8);
            float a0[8], a1[8];
            UNPK(aw0.x, a0[0], a0[1]) UNPK(aw0.y, a0[2], a0[3])
            UNPK(aw0.z, a0[4], a0[5]) UNPK(aw0.w, a0[6], a0[7])
            UNPK(aw1.x, a1[0], a1[1]) UNPK(aw1.y, a1[2], a1[3])
            UNPK(aw1.z, a1[4], a1[5]) UNPK(aw1.w, a1[6], a1[7])

            float p0 = 0.0f, p1 = 0.0f;
            #pragma unroll
            for (int i = 0; i < 8; ++i) {
                float d0 = a0[i] - zd[i];
                p0 += d0 * d0;
                float d1 = a1[i] - zd[i];
                p1 += d1 * d1;
            }
            p0 = row_sum16(p0);                 // full ||z_s0 - z_d||^2 (per quarter)
            p1 = row_sum16(p1);
            float w0 = v0 ? __expf(nbet * __builtin_amdgcn_sqrtf(p0 + 1e-12f)) : 0.0f;
            float w1 = v1 ? __expf(nbet * __builtin_amdgcn_sqrtf(p1 + 1e-12f)) : 0.0f;
            sden += w0 + w1;
            #pragma unroll
            for (int i = 0; i < 8; ++i) acc[i] += w0 * a0[i] + w1 * a1[i];
        }
    }

    // combine the 4 quarters (cross-row: DPP rows are 16 lanes, so use shfl here)
    #define CMB(v) v += __shfl_xor(v, 16, 64); v += __shfl_xor(v, 32, 64);
    CMB(sden)
    CMB(acc[0]) CMB(acc[1]) CMB(acc[2]) CMB(acc[3])
    CMB(acc[4]) CMB(acc[5]) CMB(acc[6]) CMB(acc[7])
    #undef CMB

    float inv = (deg > 0) ? 1.0f / sden : 0.0f;
    if (q == 0) {
        float* orow = out + (long)node * DIM + ql * 8;
        *(float4*)orow =
            make_float4(acc[0] * inv, acc[1] * inv, acc[2] * inv, acc[3] * inv);
        *(float4*)(orow + 4) =
            make_float4(acc[4] * inv, acc[5] * inv, acc[6] * inv, acc[7] * inv);
    }
}

extern "C" void kernel_launch(void* const* d_in, const int* in_sizes, int n_in,
                              void* d_out, int out_size, void* d_ws, size_t ws_size,
                              hipStream_t stream) {
    const float* h    = (const float*)d_in[0];
    const float* W    = (const float*)d_in[1];
    const float* beta = (const float*)d_in[2];
    const int* src    = (const int*)d_in[3];
    const int* dst    = (const int*)d_in[4];
    float* out = (float*)d_out;

    // workspace (4B word units).  zb = 50000*128 bf16 = 6.4M shorts = 3.2M WORDS
    //   zb   words [0, 3.2M)
    //   lst  words [3.2M, 3.2M+L)       bucket 3.2M or csr 600k
    //   cnt / cur / off / bsum / Wb after
    const size_t bucket_total = (3200000ull + 3200000 + 150000 + 256 + 8192) * 4;
    const bool use_bucket = ws_size >= bucket_total;
    const size_t lst_len = use_bucket ? 3200000 : 600000;

    float* ws  = (float*)d_ws;
    unsigned short* zb = (unsigned short*)ws;           // 3,200,000 words
    int* lst   = (int*)(ws + 3200000);                  // bucket 3.2M or csr 600k
    int* cnt   = (int*)(ws + 3200000 + lst_len);        // 50,000
    int* cur   = cnt + 50000;                           // 50,000
    int* off   = cur + 50000;                           // 50,000
    int* bsum  = off + 50000;                           //    256
    unsigned short* Wb = (unsigned short*)(bsum + 256); // 16,384 bf16 (8,192 words)

    prep_kernel<<<196, 256, 0, stream>>>(W, Wb, cur, cnt);
    if (use_bucket) {
        // 3126 blocks: bid%4==0 -> gemm (782), else -> fill (2344)
        fg_kernel<<<3126, 256, 0, stream>>>(h, Wb, zb, src, dst, cur, lst);
        node_kernel<<<N_NODES / 4, 256, 0, stream>>>(zb, lst, cur /*dummy*/, cur, BCAP,
                                                     beta, out);
    } else {
        count_kernel<<<(N_EDGES + 255) / 256, 256, 0, stream>>>(dst, cnt);
        scan_a<<<196, 256, 0, stream>>>(cnt, off, bsum);
        scan_b<<<1, 256, 0, stream>>>(bsum, 196);
        scan_c<<<196, 256, 0, stream>>>(off, cnt, bsum);
        cfill_kernel<<<(N_EDGES + 255) / 256, 256, 0, stream>>>(src, dst, off, cur, lst);
        gemm_kernel<<<(N_NODES / 16 + 3) / 4, 256, 0, stream>>>(h, Wb, zb);
        node_kernel<<<N_NODES / 4, 256, 0, stream>>>(zb, lst, off, cnt, 0, beta, out);
    }
}